// Round 3
// baseline (1350.706 us; speedup 1.0000x reference)
//
#include <hip/hip_runtime.h>
#include <hip/hip_bf16.h>

// ---------------------------------------------------------------------------
// MLPpara fused:  out = softmax( selu( selu( (mag ⊙ (x@W_pre[e]) + b_pre[e])
//                        @ W_share + b_share ) @ W1 + b1 ) @ W2 + b2 )
// 512 blocks = 256 experts x 2 M-halves (128 rows each); 256 thr = 4 waves.
// 2 blocks/CU (LDS 61440) -> independent barrier groups overlap stalls.
// BK=64 per barrier step (2 k32 slices), depth-2 W prefetch, lgkm-only
// barriers so global prefetches stay in flight. Pair blocks (bid, bid+256)
// share expert & XCD -> twin W stream L2-hits.
// ---------------------------------------------------------------------------

typedef float  f32x4  __attribute__((ext_vector_type(4)));
typedef __bf16 bf16x8 __attribute__((ext_vector_type(8)));
typedef __bf16 bf16x4 __attribute__((ext_vector_type(4)));
typedef int    i32x2  __attribute__((ext_vector_type(2)));
typedef int    i32x4  __attribute__((ext_vector_type(4)));

#define MFMA16(a, b, c) __builtin_amdgcn_mfma_f32_16x16x32_bf16((a), (b), (c), 0, 0, 0)

static constexpr int NB = 256, NP = 512, NS = 200;

// LDS map (bytes)
static constexpr int SLICE   = 4608;            // one 64q x 32p bf16 slice, 72B pitch
static constexpr int ST_STEP = 2 * SLICE;       // BK=64 step = 2 slices
static constexpr int OFF_ST  = 0;               // dbuf: 2*9216 = 18432
static constexpr int OFF_HT  = 18432;           // h tile 128 x 144B = 18432 (end 36864)
static constexpr int H2_P    = 232;             // tail h2 pitch (elements), 464B/row
static constexpr int OFF_H2  = 0;               // overlay after full sync; 128*464=59392
static constexpr int OFF_PART = 59392;          // 256*2*4 = 2048
static constexpr int SMEM_BYTES = 61440;        // 2 blocks/CU

#define LGKM_BARRIER()                                        \
    do {                                                      \
        asm volatile("s_waitcnt lgkmcnt(0)" ::: "memory");    \
        __builtin_amdgcn_s_barrier();                         \
    } while (0)

// ---------------------------- prep kernels ---------------------------------

// x [256][512] f32 -> A-frag order bf16: ((k32*16 + r16)*64 + lane)*8 + e
__global__ void prep_xf(const float* __restrict__ x, __bf16* __restrict__ xf) {
    int t   = blockIdx.x * 256 + threadIdx.x;    // 16384 total
    int l   = t & 63;
    int r16 = (t >> 6) & 15;
    int k32 = t >> 10;
    const float* src = x + (r16 * 16 + (l & 15)) * NP + k32 * 32 + (l >> 4) * 8;
    bf16x8 v;
#pragma unroll
    for (int e = 0; e < 8; e++) v[e] = (__bf16)src[e];
    *(bf16x8*)(xf + (size_t)t * 8) = v;
}

// W_share [512][200] f32 -> B-frag order, padded to 224 cols, bf16.
__global__ void prep_ws(const float* __restrict__ Ws, __bf16* __restrict__ wf) {
    int i = blockIdx.x * 256 + threadIdx.x;      // 114688 total
    int e8  = i & 7;
    int l   = (i >> 3) & 63;
    int n16 = (i >> 9) % 14;
    int k32 = (i >> 9) / 14;
    int q = k32 * 32 + (l >> 4) * 8 + e8;
    int s = n16 * 16 + (l & 15);
    float v = (s < NS) ? Ws[q * NS + s] : 0.0f;
    wf[i] = (__bf16)v;
}

// ---------------------------- step macros ----------------------------------
// Step S covers k32 = (S&7)*2 + {0,1} of nt-tile (S>>3). 64 steps total.

#define X_LOAD(SN, XDST)                                                      \
    if ((SN) < 64) {                                                          \
        const int kb_ = ((SN) & 7) * 2;                                       \
        _Pragma("unroll")                                                     \
        for (int kk_ = 0; kk_ < 2; kk_++)                                     \
            _Pragma("unroll")                                                 \
            for (int i_ = 0; i_ < 4; i_++)                                    \
                XDST[kk_ * 4 + i_] =                                          \
                    *(const bf16x8*)(xfw + (kb_ + kk_) * 8192 + i_ * 512);    \
    }

#define W_GATHER(S2, WDST)                                                    \
    if ((S2) < 64) {                                                          \
        const int nt2_ = (S2) >> 3;                                           \
        const int kb2_ = ((S2) & 7) * 2;                                      \
        _Pragma("unroll")                                                     \
        for (int sub_ = 0; sub_ < 2; sub_++)                                  \
            _Pragma("unroll")                                                 \
            for (int pp_ = 0; pp_ < 2; pp_++)                                 \
                _Pragma("unroll")                                             \
                for (int i_ = 0; i_ < 4; i_++)                                \
                    WDST[sub_ * 8 + pp_ * 4 + i_] =                           \
                        WpreE[(size_t)((kb2_ + sub_) * 32 + pp_ * 16 + p0 + i_) * NP \
                              + nt2_ * 64 + q];                               \
    }

#define W_WRITE(S1, WSRC)                                                     \
    if ((S1) < 64) {                                                          \
        char* wb_ = smem + OFF_ST + ((S1) & 1) * ST_STEP;                     \
        _Pragma("unroll")                                                     \
        for (int sub_ = 0; sub_ < 2; sub_++)                                  \
            _Pragma("unroll")                                                 \
            for (int pp_ = 0; pp_ < 2; pp_++) {                               \
                bf16x4 wv_;                                                   \
                _Pragma("unroll")                                             \
                for (int i_ = 0; i_ < 4; i_++)                                \
                    wv_[i_] = (__bf16)WSRC[sub_ * 8 + pp_ * 4 + i_];          \
                *(bf16x4*)(wb_ + sub_ * SLICE + q * 72 + (pp_ * 16 + p0) * 2) = wv_; \
            }                                                                 \
    }

#define STEP_MFMA(S, XC)                                                      \
    {                                                                         \
        const char* stb_ = smem + OFF_ST + ((S) & 1) * ST_STEP;               \
        _Pragma("unroll")                                                     \
        for (int kk_ = 0; kk_ < 2; kk_++) {                                   \
            bf16x8 bf_[2];                                                    \
            _Pragma("unroll")                                                 \
            for (int j_ = 0; j_ < 2; j_++) {                                  \
                const int q_ = wc * 32 + j_ * 16 + l15;                       \
                union { i32x4 u; bf16x8 b; } cv_;                             \
                i32x2 lo_ = *(const i32x2*)(stb_ + kk_ * SLICE + q_ * 72 + lg * 16);     \
                i32x2 hi_ = *(const i32x2*)(stb_ + kk_ * SLICE + q_ * 72 + lg * 16 + 8); \
                cv_.u = (i32x4){lo_.x, lo_.y, hi_.x, hi_.y};                  \
                bf_[j_] = cv_.b;                                              \
            }                                                                 \
            _Pragma("unroll")                                                 \
            for (int i_ = 0; i_ < 4; i_++)                                    \
                _Pragma("unroll")                                             \
                for (int j_ = 0; j_ < 2; j_++)                                \
                    acc1[i_][j_] = MFMA16(XC[kk_ * 4 + i_], bf_[j_], acc1[i_][j_]); \
        }                                                                     \
    }

// order matters: x loads FIRST (vmcnt is in-order; MFMA's wait must not
// drain the younger HBM W loads), then W gather; ds ops after.
#define K_STEP(S, XC, XN, WC, WN)  \
    X_LOAD((S) + 1, XN)            \
    W_GATHER((S) + 2, WN)          \
    STEP_MFMA(S, XC)               \
    W_WRITE((S) + 1, WC)           \
    LGKM_BARRIER();

// ---------------------------- main kernel ----------------------------------

__global__ __launch_bounds__(256, 2) void fused_experts(
    const float* __restrict__ mag,     // [E][B]
    const float* __restrict__ Wpre,    // [E][P][P]
    const float* __restrict__ bpre,    // [E][P]
    const float* __restrict__ bshare,  // [S]
    const float* __restrict__ W1,      // [S][T]
    const float* __restrict__ b1,      // [T]
    const float* __restrict__ W2,      // [T][2]
    const float* __restrict__ b2,      // [2]
    const __bf16* __restrict__ xf,     // x in A-frag order
    const __bf16* __restrict__ wsf,    // W_share B-frags
    float* __restrict__ out)           // [E*B][2]
{
    __shared__ __align__(16) char smem[SMEM_BYTES];

    const int bid  = blockIdx.x;
    const int e    = bid & 255;        // pair (bid, bid+256): same expert, same XCD
    const int mh   = bid >> 8;         // M half: rows [mh*128, +128)
    const int tid  = threadIdx.x;
    const int lane = tid & 63;
    const int wid  = tid >> 6;
    const int wr   = wid >> 1;         // 0..1 : 64-row band within half
    const int wc   = wid & 1;          // 0..1 : N half
    const int l15  = lane & 15;
    const int lg   = lane >> 4;

    // W staging role: wave wid covers p0 = wid*4 (+{0..3}, +pp*16, per sub-slice)
    const int q  = lane;
    const int p0 = wid * 4;

    const float* WpreE = Wpre + (size_t)e * NP * NP;
    const __bf16* xfw  = xf + ((mh * 8 + wr * 4) * 64 + lane) * 8;
    __bf16* ht = (__bf16*)(smem + OFF_HT);

    f32x4 magv[4];
#pragma unroll
    for (int i = 0; i < 4; i++)
        magv[i] = *(const f32x4*)(mag + e * NB + mh * 128 + wr * 64 + i * 16 + lg * 4);

    f32x4 acc2[4][7];
#pragma unroll
    for (int i = 0; i < 4; i++)
#pragma unroll
        for (int j = 0; j < 7; j++) acc2[i][j] = (f32x4){0.f, 0.f, 0.f, 0.f};
    f32x4 acc1[4][2];
#pragma unroll
    for (int i = 0; i < 4; i++)
#pragma unroll
        for (int j = 0; j < 2; j++) acc1[i][j] = (f32x4){0.f, 0.f, 0.f, 0.f};

    bf16x8 XA[8], XB[8];
    float  WA[16], WB[16];
    bf16x8 wfr[14];

    // ---- prologue: x(0); W slices 0,1 gathered; slice 0 -> LDS buf0 ----
    X_LOAD(0, XA)
    W_GATHER(0, WA)
    W_GATHER(1, WB)
    W_WRITE(0, WA)
    LGKM_BARRIER();

    for (int nt = 0; nt < 8; ++nt) {
        const int S0 = nt * 8;

        // nt-start prefetch (issued oldest so later vmcnt waits stay weak):
        // W_share frags + b_pre for this tile into registers.
#pragma unroll
        for (int kk = 0; kk < 2; kk++)
#pragma unroll
            for (int j2 = 0; j2 < 7; j2++)
                wfr[kk * 7 + j2] = *(const bf16x8*)(wsf +
                    (size_t)((((nt * 2 + kk) * 14) + wc * 7 + j2) * 64 + lane) * 8);
        const float bp0 = bpre[e * NP + nt * 64 + wc * 32 + l15];
        const float bp1 = bpre[e * NP + nt * 64 + wc * 32 + 16 + l15];

        K_STEP(S0 + 0, XA, XB, WB, WA)
        K_STEP(S0 + 1, XB, XA, WA, WB)
        K_STEP(S0 + 2, XA, XB, WB, WA)
        K_STEP(S0 + 3, XB, XA, WA, WB)
        K_STEP(S0 + 4, XA, XB, WB, WA)
        K_STEP(S0 + 5, XB, XA, WA, WB)
        K_STEP(S0 + 6, XA, XB, WB, WA)
        K_STEP(S0 + 7, XB, XA, WA, WB)

        // ---- h = mag*Y + b_pre -> bf16 h-tile (D: col=l15, row=lg*4+r) ----
#pragma unroll
        for (int j = 0; j < 2; j++) {
            const float bp = j ? bp1 : bp0;
#pragma unroll
            for (int i = 0; i < 4; i++)
#pragma unroll
                for (int r = 0; r < 4; r++) {
                    const float h = magv[i][r] * acc1[i][j][r] + bp;
                    ht[(wr * 64 + i * 16 + lg * 4 + r) * 72 + wc * 32 + j * 16 + l15] = (__bf16)h;
                }
        }
        LGKM_BARRIER();

        // ---- GEMM2 partial: Z += h_tile[128x64] @ W_share_frag[64x224] ----
#pragma unroll
        for (int kk = 0; kk < 2; kk++) {
            bf16x8 a2[4];
#pragma unroll
            for (int i = 0; i < 4; i++)
                a2[i] = *(const bf16x8*)(ht + (wr * 64 + i * 16 + l15) * 72 + kk * 32 + lg * 8);
#pragma unroll
            for (int i = 0; i < 4; i++)
#pragma unroll
                for (int j2 = 0; j2 < 7; j2++)
                    acc2[i][j2] = MFMA16(a2[i], wfr[kk * 7 + j2], acc2[i][j2]);
        }

#pragma unroll
        for (int i = 0; i < 4; i++)
#pragma unroll
            for (int j = 0; j < 2; j++) acc1[i][j] = (f32x4){0.f, 0.f, 0.f, 0.f};
    }

    __syncthreads();   // full drain once; tail overlays LDS

    // ------------------------------ tail -----------------------------------
    __bf16* h2  = (__bf16*)(smem + OFF_H2);
    float* part = (float*)(smem + OFF_PART);
    const float SC = 1.0507009873554805f;
    const float AL = 1.6732632423543772f;

    // h2 = selu(Z + b_share) bf16  [128 rows x 224 cols]
#pragma unroll
    for (int j2 = 0; j2 < 7; j2++) {
        const int s = wc * 112 + j2 * 16 + l15;
        const float bs = (s < NS) ? bshare[s] : 0.0f;
#pragma unroll
        for (int i = 0; i < 4; i++) {
            const int b0 = wr * 64 + i * 16 + lg * 4;
#pragma unroll
            for (int r = 0; r < 4; r++) {
                float z = acc2[i][j2][r] + bs;
                z = (z > 0.f) ? SC * z : SC * AL * (__expf(z) - 1.f);
                h2[(b0 + r) * H2_P + s] = (__bf16)z;
            }
        }
    }
    __syncthreads();

    // GEMM3 (200->20) + SELU + partial GEMM4 (f32 VALU); 2 threads per row
    {
        const int b  = tid & 127;
        const int th = tid >> 7;      // wave-uniform
        float u[10];
#pragma unroll
        for (int j = 0; j < 10; j++) u[j] = b1[th * 10 + j];
        for (int s8 = 0; s8 < NS; s8 += 8) {
            bf16x8 hv = *(const bf16x8*)(h2 + b * H2_P + s8);
#pragma unroll
            for (int so = 0; so < 8; so++) {
                const float v = (float)hv[so];
                const float* w1row = W1 + (s8 + so) * 20 + th * 10;
#pragma unroll
                for (int j = 0; j < 10; j++) u[j] = fmaf(v, w1row[j], u[j]);
            }
        }
        float pa = 0.f, pb = 0.f;
#pragma unroll
        for (int j = 0; j < 10; j++) {
            float v = u[j];
            v = (v > 0.f) ? SC * v : SC * AL * (__expf(v) - 1.f);
            const int t = th * 10 + j;
            pa = fmaf(v, W2[t * 2 + 0], pa);
            pb = fmaf(v, W2[t * 2 + 1], pb);
        }
        part[tid * 2 + 0] = pa;
        part[tid * 2 + 1] = pb;
    }
    __syncthreads();

    if (tid < 128) {
        const int b = tid;
        const float l0 = part[b * 2 + 0] + part[(b + 128) * 2 + 0] + b2[0];
        const float l1 = part[b * 2 + 1] + part[(b + 128) * 2 + 1] + b2[1];
        const float mx  = fmaxf(l0, l1);
        const float ex0 = __expf(l0 - mx), ex1 = __expf(l1 - mx);
        const float inv = 1.0f / (ex0 + ex1);
        const size_t g = (size_t)e * NB + mh * 128 + b;
        out[g * 2 + 0] = ex0 * inv;
        out[g * 2 + 1] = ex1 * inv;
    }
}

// ---------------------------- launcher -------------------------------------

extern "C" void kernel_launch(void* const* d_in, const int* in_sizes, int n_in,
                              void* d_out, int out_size, void* d_ws, size_t ws_size,
                              hipStream_t stream) {
    const float* x      = (const float*)d_in[0];
    const float* mag    = (const float*)d_in[1];
    const float* Wpre   = (const float*)d_in[2];
    const float* bpre   = (const float*)d_in[3];
    const float* Wshare = (const float*)d_in[4];
    const float* bshare = (const float*)d_in[5];
    const float* W1     = (const float*)d_in[6];
    const float* b1     = (const float*)d_in[7];
    const float* W2     = (const float*)d_in[8];
    const float* b2     = (const float*)d_in[9];
    float* out = (float*)d_out;

    __bf16* xf  = (__bf16*)d_ws;                     // 262144 B
    __bf16* wsf = (__bf16*)((char*)d_ws + 262144);   // 229376 B

    prep_xf<<<64, 256, 0, stream>>>(x, xf);
    prep_ws<<<448, 256, 0, stream>>>(Wshare, wsf);
    fused_experts<<<512, 256, 0, stream>>>(mag, Wpre, bpre, bshare, W1, b1,
                                           W2, b2, xf, wsf, out);
}

// Round 4
// 519.187 us; speedup vs baseline: 2.6016x; 2.6016x over previous
//
#include <hip/hip_runtime.h>
#include <hip/hip_bf16.h>

// ---------------------------------------------------------------------------
// MLPpara fused:  out = softmax( selu( selu( (mag ⊙ (x@W_pre[e]) + b_pre[e])
//                        @ W_share + b_share ) @ W1 + b1 ) @ W2 + b2 )
// Two-phase design:
//   prep_w: W_pre f32 [E][512][512] -> bf16 MFMA-B-fragment order (134 MB).
//   fused_experts: 256 blocks (1 expert/CU) x 512 thr (8 waves, 4M x 2N).
//     W staged by global_load_lds (1 dwordx4/wave/step), 6-slab LDS ring,
//     counted vmcnt before each barrier (prefetches never drained).
// ---------------------------------------------------------------------------

typedef float  f32x4  __attribute__((ext_vector_type(4)));
typedef __bf16 bf16x8 __attribute__((ext_vector_type(8)));

#define MFMA16(a, b, c) __builtin_amdgcn_mfma_f32_16x16x32_bf16((a), (b), (c), 0, 0, 0)

static constexpr int NB = 256, NP = 512, NS = 200;

// LDS map (bytes) for fused kernel
static constexpr int OFF_RING = 0;          // 6 slabs x 8192 = 49152
static constexpr int OFF_HT   = 49152;      // h tile 256 rows x 144B = 36864 (end 86016)
static constexpr int H2_P     = 232;        // tail h2 pitch (elems)
static constexpr int OFF_H2   = 0;          // overlay after full sync: 256*464 = 118784
static constexpr int OFF_PART = 118784;     // 512*2*4 = 4096
static constexpr int SMEM_BYTES = 122880;

#define VM_WAIT(N) asm volatile("s_waitcnt vmcnt(" #N ")" ::: "memory")
#define LGKM_BARRIER()                                        \
    do {                                                      \
        asm volatile("s_waitcnt lgkmcnt(0)" ::: "memory");    \
        __builtin_amdgcn_s_barrier();                         \
    } while (0)

// ---------------------------- prep kernels ---------------------------------

// x [256][512] f32 -> A-frag order bf16: ((k32*16 + r16)*64 + lane)*8 + e
__global__ void prep_xf(const float* __restrict__ x, __bf16* __restrict__ xf) {
    int t   = blockIdx.x * 256 + threadIdx.x;    // 16384 total
    int l   = t & 63;
    int r16 = (t >> 6) & 15;
    int k32 = t >> 10;
    const float* src = x + (r16 * 16 + (l & 15)) * NP + k32 * 32 + (l >> 4) * 8;
    bf16x8 v;
#pragma unroll
    for (int e = 0; e < 8; e++) v[e] = (__bf16)src[e];
    *(bf16x8*)(xf + (size_t)t * 8) = v;
}

// W_share [512][200] f32 -> B-frag order, padded to 224 cols, bf16.
__global__ void prep_ws(const float* __restrict__ Ws, __bf16* __restrict__ wf) {
    int i = blockIdx.x * 256 + threadIdx.x;      // 114688 total
    int e8  = i & 7;
    int l   = (i >> 3) & 63;
    int n16 = (i >> 9) % 14;
    int k32 = (i >> 9) / 14;
    int q = k32 * 32 + (l >> 4) * 8 + e8;
    int s = n16 * 16 + (l & 15);
    float v = (s < NS) ? Ws[q * NS + s] : 0.0f;
    wf[i] = (__bf16)v;
}

// W_pre [E][512][512] f32 -> wpb bf16 frag slices.
// slice s = nt*16 + k32 (128/expert, 4KB each):
//   wpb[(e*128+s)*2048 + (n16*64+l)*8 + ee] =
//       bf16( W_pre[e][ k32*32 + (l>>4)*8 + ee ][ nt*64 + n16*16 + (l&15) ] )
// block: 256 thr = 4 slices (e, nt fixed; k32 = kq*4..+3): 128p x 64q f32 tile.
__global__ __launch_bounds__(256) void prep_w(const float* __restrict__ Wp,
                                              __bf16* __restrict__ wpb) {
    __shared__ float tile[128][65];              // 33280 B
    const int blk = blockIdx.x;                  // 8192
    const int e   = blk >> 5;
    const int sb  = blk & 31;
    const int nt  = sb >> 2;
    const int kq  = sb & 3;
    const int t   = threadIdx.x;
    const int pr  = t >> 4;
    const int pc  = (t & 15) * 4;
    const float* src = Wp + (size_t)e * 262144 + (size_t)(kq * 128) * 512 + nt * 64;
#pragma unroll
    for (int rr = 0; rr < 8; ++rr) {
        const int p = rr * 16 + pr;
        f32x4 v = *(const f32x4*)(src + (size_t)p * 512 + pc);
        tile[p][pc + 0] = v.x; tile[p][pc + 1] = v.y;
        tile[p][pc + 2] = v.z; tile[p][pc + 3] = v.w;
    }
    __syncthreads();
#pragma unroll
    for (int ff = 0; ff < 4; ++ff) {
        const int f   = ff * 256 + t;            // 0..1023
        const int l   = f & 63;
        const int n16 = (f >> 6) & 3;
        const int sl  = f >> 8;                  // k32 = kq*4 + sl
        const int lp  = sl * 32 + (l >> 4) * 8;
        const int lq  = n16 * 16 + (l & 15);
        bf16x8 o;
#pragma unroll
        for (int ee = 0; ee < 8; ++ee) o[ee] = (__bf16)tile[lp + ee][lq];
        const size_t s = (size_t)(nt * 16 + kq * 4 + sl);
        *(bf16x8*)(wpb + ((size_t)e * 128 + s) * 2048 + (size_t)(n16 * 64 + l) * 8) = o;
    }
}

// ---------------------------- step macros ----------------------------------
// 64 steps; step S = W slices {2S, 2S+1} (nt = S>>3), x k32 = (S&7)*2 + {0,1}.

#define GLL_ISSUE(SG)                                                         \
    __builtin_amdgcn_global_load_lds(                                         \
        (const __attribute__((address_space(1))) unsigned int*)(wp + (size_t)(SG) * 8192), \
        (__attribute__((address_space(3))) unsigned int*)(void*)(smem + OFF_RING + ((SG) % 6) * 8192 + wid * 1024), \
        16, 0, 0);

#define X_LOAD(SN, XD)                                                        \
    {                                                                         \
        const int kb_ = ((SN) & 7) * 2;                                       \
        _Pragma("unroll")                                                     \
        for (int kk_ = 0; kk_ < 2; kk_++)                                     \
            _Pragma("unroll")                                                 \
            for (int i_ = 0; i_ < 4; i_++)                                    \
                XD[kk_ * 4 + i_] =                                            \
                    *(const bf16x8*)(xfw + (kb_ + kk_) * 8192 + i_ * 512);    \
    }

#define STEP_MFMA(S, XC)                                                      \
    {                                                                         \
        const char* slab_ = smem + OFF_RING + ((S) % 6) * 8192;               \
        _Pragma("unroll")                                                     \
        for (int kk_ = 0; kk_ < 2; kk_++) {                                   \
            bf16x8 bf_[2];                                                    \
            _Pragma("unroll")                                                 \
            for (int j_ = 0; j_ < 2; j_++)                                    \
                bf_[j_] = *(const bf16x8*)(slab_ + kk_ * 4096 +               \
                               (wc * 2 + j_) * 1024 + lane * 16);             \
            _Pragma("unroll")                                                 \
            for (int i_ = 0; i_ < 4; i_++)                                    \
                _Pragma("unroll")                                             \
                for (int j_ = 0; j_ < 2; j_++)                                \
                    acc1[i_][j_] = MFMA16(XC[kk_ * 4 + i_], bf_[j_], acc1[i_][j_]); \
        }                                                                     \
    }

// wait (before barrier!) until gll(S+1) retired: younger = glls S+2..min(S+5,63)
// + x(S+1) (8). Interior: 4+8=12.
#define END_SYNC(S)                                                           \
    {                                                                         \
        if ((S) <= 58)      VM_WAIT(12);                                      \
        else if ((S) == 59) VM_WAIT(11);                                      \
        else if ((S) == 60) VM_WAIT(10);                                      \
        else if ((S) == 61) VM_WAIT(9);                                       \
        else if ((S) == 62) VM_WAIT(8);                                       \
        LGKM_BARRIER();                                                       \
    }

#define H_PHASE(NT)                                                           \
    {                                                                         \
        const int nt_ = (NT);                                                 \
        const float bp0_ = bpre[e * NP + nt_ * 64 + wc * 32 + l15];           \
        const float bp1_ = bpre[e * NP + nt_ * 64 + wc * 32 + 16 + l15];      \
        _Pragma("unroll")                                                     \
        for (int i_ = 0; i_ < 4; i_++) {                                      \
            f32x4 mg_ = *(const f32x4*)(mag + e * NB + wr * 64 + i_ * 16 + lg * 4); \
            _Pragma("unroll")                                                 \
            for (int r_ = 0; r_ < 4; r_++) {                                  \
                const int row_ = wr * 64 + i_ * 16 + lg * 4 + r_;             \
                ht[row_ * 72 + wc * 32 + l15]      = (__bf16)(mg_[r_] * acc1[i_][0][r_] + bp0_); \
                ht[row_ * 72 + wc * 32 + 16 + l15] = (__bf16)(mg_[r_] * acc1[i_][1][r_] + bp1_); \
            }                                                                 \
        }                                                                     \
    }

#define GEMM2_PHASE(NT)                                                       \
    {                                                                         \
        const int nt_ = (NT);                                                 \
        _Pragma("unroll")                                                     \
        for (int kk_ = 0; kk_ < 2; kk_++) {                                   \
            bf16x8 wfr_[7];                                                   \
            _Pragma("unroll")                                                 \
            for (int j2_ = 0; j2_ < 7; j2_++)                                 \
                wfr_[j2_] = *(const bf16x8*)(wsf +                            \
                    (size_t)((((nt_ * 2 + kk_) * 14) + wc * 7 + j2_) * 64 + lane) * 8); \
            bf16x8 a2_[4];                                                    \
            _Pragma("unroll")                                                 \
            for (int i_ = 0; i_ < 4; i_++)                                    \
                a2_[i_] = *(const bf16x8*)(ht + (wr * 64 + i_ * 16 + l15) * 72 + kk_ * 32 + lg * 8); \
            _Pragma("unroll")                                                 \
            for (int i_ = 0; i_ < 4; i_++)                                    \
                _Pragma("unroll")                                             \
                for (int j2_ = 0; j2_ < 7; j2_++)                             \
                    acc2[i_][j2_] = MFMA16(a2_[i_], wfr_[j2_], acc2[i_][j2_]); \
        }                                                                     \
        _Pragma("unroll")                                                     \
        for (int i_ = 0; i_ < 4; i_++)                                        \
            _Pragma("unroll")                                                 \
            for (int j_ = 0; j_ < 2; j_++)                                    \
                acc1[i_][j_] = (f32x4){0.f, 0.f, 0.f, 0.f};                   \
    }

#define K_STEP(S, XC, XN)                                                     \
    {                                                                         \
        if ((S) <= 62) { X_LOAD((S) + 1, XN) }                                \
        if ((S) <= 58) { GLL_ISSUE((S) + 5) }                                 \
        STEP_MFMA(S, XC)                                                      \
        if (((S) & 7) == 7) {                                                 \
            H_PHASE((S) >> 3)                                                 \
            END_SYNC(S)                                                       \
            GEMM2_PHASE((S) >> 3)                                             \
        } else {                                                              \
            END_SYNC(S)                                                       \
        }                                                                     \
    }

// ---------------------------- main kernel ----------------------------------

__global__ __launch_bounds__(512) void fused_experts(
    const float* __restrict__ mag,     // [E][B]
    const float* __restrict__ bpre,    // [E][P]
    const float* __restrict__ bshare,  // [S]
    const float* __restrict__ W1,      // [S][T]
    const float* __restrict__ b1,      // [T]
    const float* __restrict__ W2,      // [T][2]
    const float* __restrict__ b2,      // [2]
    const __bf16* __restrict__ xf,     // x A-frags
    const __bf16* __restrict__ wsf,    // W_share B-frags
    const __bf16* __restrict__ wpb,    // W_pre B-frag slices (bf16)
    float* __restrict__ out)           // [E*B][2]
{
    __shared__ __align__(16) char smem[SMEM_BYTES];

    const int e    = blockIdx.x;
    const int tid  = threadIdx.x;
    const int lane = tid & 63;
    const int wid  = tid >> 6;         // 0..7
    const int wr   = wid >> 1;         // 0..3 : 64-row band
    const int wc   = wid & 1;          // 0..1 : N half
    const int l15  = lane & 15;
    const int lg   = lane >> 4;

    // gll role: wave wid stages 1KB of each 8KB slab (kk = wid>>2, n16 = wid&3)
    const char* wp = (const char*)wpb + (size_t)e * 524288
                     + (wid >> 2) * 4096 + (wid & 3) * 1024 + lane * 16;
    const __bf16* xfw = xf + ((wr * 4) * 64 + lane) * 8;
    __bf16* ht = (__bf16*)(smem + OFF_HT);

    f32x4 acc2[4][7];
#pragma unroll
    for (int i = 0; i < 4; i++)
#pragma unroll
        for (int j = 0; j < 7; j++) acc2[i][j] = (f32x4){0.f, 0.f, 0.f, 0.f};
    f32x4 acc1[4][2];
#pragma unroll
    for (int i = 0; i < 4; i++)
#pragma unroll
        for (int j = 0; j < 2; j++) acc1[i][j] = (f32x4){0.f, 0.f, 0.f, 0.f};

    bf16x8 XA[8], XB[8];

    // ---- prologue: 5 slabs in flight, x(0) loaded ----
    GLL_ISSUE(0) GLL_ISSUE(1) GLL_ISSUE(2) GLL_ISSUE(3) GLL_ISSUE(4)
    X_LOAD(0, XA)
    VM_WAIT(12);          // gll(0) retired (4 glls + 8 x younger)
    LGKM_BARRIER();

    for (int Sp = 0; Sp < 64; Sp += 2) {
        K_STEP(Sp,     XA, XB)
        K_STEP(Sp + 1, XB, XA)
    }

    __syncthreads();   // full drain; tail overlays LDS

    // ------------------------------ tail -----------------------------------
    __bf16* h2  = (__bf16*)(smem + OFF_H2);
    float* part = (float*)(smem + OFF_PART);
    const float SC = 1.0507009873554805f;
    const float AL = 1.6732632423543772f;

    // h2 = selu(Z + b_share) bf16  [256 rows x 224 cols]
#pragma unroll
    for (int j2 = 0; j2 < 7; j2++) {
        const int s = wc * 112 + j2 * 16 + l15;
        const float bs = (s < NS) ? bshare[s] : 0.0f;
#pragma unroll
        for (int i = 0; i < 4; i++) {
            const int b0 = wr * 64 + i * 16 + lg * 4;
#pragma unroll
            for (int r = 0; r < 4; r++) {
                float z = acc2[i][j2][r] + bs;
                z = (z > 0.f) ? SC * z : SC * AL * (__expf(z) - 1.f);
                h2[(b0 + r) * H2_P + s] = (__bf16)z;
            }
        }
    }
    __syncthreads();

    // GEMM3 (200->20) + SELU + partial GEMM4 (f32 VALU)
    {
        const int b  = tid & 255;
        const int th = tid >> 8;      // wave-uniform
        float u[10];
#pragma unroll
        for (int j = 0; j < 10; j++) u[j] = b1[th * 10 + j];
        for (int s8 = 0; s8 < NS; s8 += 8) {
            bf16x8 hv = *(const bf16x8*)(h2 + b * H2_P + s8);
#pragma unroll
            for (int so = 0; so < 8; so++) {
                const float v = (float)hv[so];
                const float* w1row = W1 + (s8 + so) * 20 + th * 10;
#pragma unroll
                for (int j = 0; j < 10; j++) u[j] = fmaf(v, w1row[j], u[j]);
            }
        }
        float pa = 0.f, pb = 0.f;
#pragma unroll
        for (int j = 0; j < 10; j++) {
            float v = u[j];
            v = (v > 0.f) ? SC * v : SC * AL * (__expf(v) - 1.f);
            const int t = th * 10 + j;
            pa = fmaf(v, W2[t * 2 + 0], pa);
            pb = fmaf(v, W2[t * 2 + 1], pb);
        }
        part[tid * 2 + 0] = pa;
        part[tid * 2 + 1] = pb;
    }
    __syncthreads();

    if (tid < 256) {
        const int b = tid;
        const float l0 = part[b * 2 + 0] + part[(b + 256) * 2 + 0] + b2[0];
        const float l1 = part[b * 2 + 1] + part[(b + 256) * 2 + 1] + b2[1];
        const float mx  = fmaxf(l0, l1);
        const float ex0 = __expf(l0 - mx), ex1 = __expf(l1 - mx);
        const float inv = 1.0f / (ex0 + ex1);
        out[((size_t)e * NB + b) * 2 + 0] = ex0 * inv;
        out[((size_t)e * NB + b) * 2 + 1] = ex1 * inv;
    }
}

// ---------------------------- launcher -------------------------------------

extern "C" void kernel_launch(void* const* d_in, const int* in_sizes, int n_in,
                              void* d_out, int out_size, void* d_ws, size_t ws_size,
                              hipStream_t stream) {
    const float* x      = (const float*)d_in[0];
    const float* mag    = (const float*)d_in[1];
    const float* Wpre   = (const float*)d_in[2];
    const float* bpre   = (const float*)d_in[3];
    const float* Wshare = (const float*)d_in[4];
    const float* bshare = (const float*)d_in[5];
    const float* W1     = (const float*)d_in[6];
    const float* b1     = (const float*)d_in[7];
    const float* W2     = (const float*)d_in[8];
    const float* b2     = (const float*)d_in[9];
    float* out = (float*)d_out;

    __bf16* xf  = (__bf16*)d_ws;                       // 262144 B
    __bf16* wsf = (__bf16*)((char*)d_ws + 262144);     // 229376 B
    __bf16* wpb = (__bf16*)((char*)d_ws + 524288);     // 134217728 B

    prep_w <<<8192, 256, 0, stream>>>(Wpre, wpb);
    prep_xf<<<64,   256, 0, stream>>>(x, xf);
    prep_ws<<<448,  256, 0, stream>>>(Wshare, wsf);
    fused_experts<<<256, 512, 0, stream>>>(mag, bpre, bshare, W1, b1, W2, b2,
                                           xf, wsf, wpb, out);
}